// Round 2
// baseline (509.269 us; speedup 1.0000x reference)
//
#include <hip/hip_runtime.h>

typedef _Float16 f16x8 __attribute__((ext_vector_type(8)));
typedef _Float16 f16x4 __attribute__((ext_vector_type(4)));
typedef float    f32x4 __attribute__((ext_vector_type(4)));
typedef unsigned long long u64;

constexpr int Bc = 4, Hc = 16, Sc = 2048, Dc = 64;
constexpr int QBLK = 64, KVBLK = 64;
constexpr int NQ  = Sc / QBLK;    // 32
constexpr int NKV = Sc / KVBLK;   // 32

__device__ __forceinline__ float fast_exp2(float x) {
#if __has_builtin(__builtin_amdgcn_exp2f)
  return __builtin_amdgcn_exp2f(x);
#else
  return exp2f(x);
#endif
}

// ---------------- Prepass A: K fp32 -> fp16 (same layout) ----------------
__global__ __launch_bounds__(256)
void cvt_k(const float* __restrict__ K, _Float16* __restrict__ K16) {
  const size_t i = (size_t)blockIdx.x * 256 + threadIdx.x;  // 8 elems/thread
  const float4 a = ((const float4*)K)[2 * i];
  const float4 b = ((const float4*)K)[2 * i + 1];
  f16x8 h = {(_Float16)a.x, (_Float16)a.y, (_Float16)a.z, (_Float16)a.w,
             (_Float16)b.x, (_Float16)b.y, (_Float16)b.z, (_Float16)b.w};
  *(f16x8*)(K16 + i * 8) = h;
}

// ---------------- Prepass B: V fp32 [bh][s][d] -> fp16 [bh][d][s] ----------------
__global__ __launch_bounds__(256)
void transpose_v(const float* __restrict__ V, _Float16* __restrict__ Vt) {
  __shared__ float tile[64][68];
  const int bh = blockIdx.x >> 5;
  const int st = blockIdx.x & 31;
  const int t  = threadIdx.x;
  const int r  = t >> 2, c0 = (t & 3) * 16;
  const float* src = V + ((size_t)bh * Sc + (size_t)st * 64 + r) * Dc + c0;
  #pragma unroll
  for (int j = 0; j < 16; j += 4)
    *(float4*)&tile[r][c0 + j] = *(const float4*)(src + j);
  __syncthreads();
  const int d = r, s0 = c0;
  _Float16* dst = Vt + ((size_t)bh * Dc + d) * Sc + (size_t)st * 64 + s0;
  f16x8 h0, h1;
  #pragma unroll
  for (int j = 0; j < 8; ++j) h0[j] = (_Float16)tile[s0 + j][d];
  #pragma unroll
  for (int j = 0; j < 8; ++j) h1[j] = (_Float16)tile[s0 + 8 + j][d];
  *(f16x8*)dst       = h0;
  *(f16x8*)(dst + 8) = h1;
}

// ---------------- Prepass C: mask int32 -> bits[b][qt][kv][row64] u64 ----------------
__global__ __launch_bounds__(256)
void pack_mask(const int* __restrict__ M, u64* __restrict__ MB) {
  const int gid  = blockIdx.x * 256 + threadIdx.x;
  const int wv   = gid >> 6, lane = gid & 63;
  const int kv   = wv & (NKV - 1);
  const int row  = (wv >> 5) & (Sc - 1);
  const int b    = wv >> 16;                 // Sc*NKV = 65536
  const int m    = M[((size_t)b * Sc + row) * Sc + (size_t)kv * 64 + lane];
  const u64 bits = __ballot(m != 0);
  if (lane == 0)
    MB[(((size_t)b * NQ + (row >> 6)) * NKV + kv) * 64 + (row & 63)] = bits;
}

// ---------------- Main: barrier-free flash attention, swapped QK^T ----------------
__global__ __launch_bounds__(256)
void attn_fwd2(const float* __restrict__ Q, const _Float16* __restrict__ K16,
               const _Float16* __restrict__ Vt16, const u64* __restrict__ MB,
               float* __restrict__ O)
{
  // XCD-chunked swizzle (2048 = 8 * 256): contiguous grid chunk per XCD
  const int bid   = (blockIdx.x & 7) * 256 + (blockIdx.x >> 3);
  const int qtile = bid & (NQ - 1);
  const int bh    = bid >> 5;
  const int b     = bh >> 4;
  const int q0    = qtile * QBLK;

  const int tid = threadIdx.x;
  const int w   = tid >> 6;
  const int l   = tid & 63;
  const int lg  = l >> 4;     // 0..3
  const int lc  = l & 15;     // 0..15  (= this lane's q-row within the wave)

  __shared__ _Float16 Plds[4][16][72];  // per-wave P^T: [q-local][key(64)+pad]

  // Q fragment (B operand): N=q=lc, k = ks*32 + 8*lg + e; scale*log2e folded
  f16x8 qf[2];
  {
    const float qs = 0.125f * 1.4426950408889634f;
    const float* qr = Q + ((size_t)bh * Sc + q0 + w * 16 + lc) * Dc + 8 * lg;
    #pragma unroll
    for (int ks = 0; ks < 2; ++ks) {
      f16x8 t;
      #pragma unroll
      for (int e = 0; e < 8; ++e) t[e] = (_Float16)(qr[ks * 32 + e] * qs);
      qf[ks] = t;
    }
  }

  f32x4 o_acc[4];
  #pragma unroll
  for (int nt = 0; nt < 4; ++nt) o_acc[nt] = (f32x4){0.f, 0.f, 0.f, 0.f};
  float m_run = -3.0e38f, l_run = 0.f;
  const float NEGL = -1.4426950e9f;   // -1e9 * log2(e)

  const _Float16* Kb = K16 + (size_t)bh * Sc * Dc;
  const _Float16* Vb = Vt16 + ((size_t)bh * Dc + lc) * Sc + 8 * lg;
  const u64*      Mb = MB + (size_t)(b * NQ + qtile) * NKV * 64 + (w * 16 + lc);

  for (int kv = 0; kv < NKV; ++kv) {
    const u64 mbits = Mb[(size_t)kv * 64];

    // K fragments (A operand): M=key=nt*16+lc, k = ks*32+8*lg+e — straight from L1/L2
    const _Float16* Kt = Kb + ((size_t)kv * KVBLK + lc) * Dc + 8 * lg;
    f16x8 kf[4][2];
    #pragma unroll
    for (int nt = 0; nt < 4; ++nt)
      #pragma unroll
      for (int ks = 0; ks < 2; ++ks)
        kf[nt][ks] = *(const f16x8*)(Kt + (size_t)nt * 16 * Dc + ks * 32);

    // S^T = K Q^T : acc[nt][r] = S[key=nt*16+4*lg+r][q=lc]
    f32x4 s_acc[4];
    #pragma unroll
    for (int nt = 0; nt < 4; ++nt) {
      f32x4 acc = (f32x4){0.f, 0.f, 0.f, 0.f};
      #pragma unroll
      for (int ks = 0; ks < 2; ++ks)
        acc = __builtin_amdgcn_mfma_f32_16x16x32_f16(kf[nt][ks], qf[ks], acc, 0, 0, 0);
      s_acc[nt] = acc;
    }

    // V^T fragments issued now; ~300cy of softmax VALU below hides their latency
    const _Float16* Vt = Vb + (size_t)kv * KVBLK;
    f16x8 vf[4][2];
    #pragma unroll
    for (int nt = 0; nt < 4; ++nt)
      #pragma unroll
      for (int ks = 0; ks < 2; ++ks)
        vf[nt][ks] = *(const f16x8*)(Vt + (size_t)nt * 16 * Sc + ks * 32);

    // mask select from packed bits
    float p[4][4];
    #pragma unroll
    for (int nt = 0; nt < 4; ++nt) {
      const unsigned b4 = ((unsigned)(mbits >> (nt * 16 + 4 * lg))) & 0xFu;
      #pragma unroll
      for (int r = 0; r < 4; ++r)
        p[nt][r] = ((b4 >> r) & 1u) ? s_acc[nt][r] : NEGL;
    }

    // online softmax for q=lc: in-lane max over 16, then xor16/xor32 across lg
    float mx = p[0][0];
    #pragma unroll
    for (int nt = 0; nt < 4; ++nt)
      #pragma unroll
      for (int r = 0; r < 4; ++r) mx = fmaxf(mx, p[nt][r]);
    mx = fmaxf(mx, __shfl_xor(mx, 16, 64));
    mx = fmaxf(mx, __shfl_xor(mx, 32, 64));
    const float mn   = fmaxf(m_run, mx);
    const float corr = fast_exp2(m_run - mn);
    m_run = mn;
    float rs = 0.f;
    #pragma unroll
    for (int nt = 0; nt < 4; ++nt)
      #pragma unroll
      for (int r = 0; r < 4; ++r) {
        const float pe = fast_exp2(p[nt][r] - mn);
        p[nt][r] = pe;
        rs += pe;
      }
    rs += __shfl_xor(rs, 16, 64);
    rs += __shfl_xor(rs, 32, 64);
    l_run = l_run * corr + rs;

    // rescale O (rows are q=4*lg+r): broadcast corr from lanes 0..15
    float cr[4];
    #pragma unroll
    for (int r = 0; r < 4; ++r) cr[r] = __shfl(corr, 4 * lg + r, 64);
    #pragma unroll
    for (int nt = 0; nt < 4; ++nt)
      #pragma unroll
      for (int r = 0; r < 4; ++r) o_acc[nt][r] *= cr[r];

    // P -> LDS as P^T[q][key]: 4 consecutive keys per write, conflict-free b64
    #pragma unroll
    for (int nt = 0; nt < 4; ++nt) {
      uint2 pk;
      pk.x = __builtin_bit_cast(unsigned, __builtin_amdgcn_cvt_pkrtz(p[nt][0], p[nt][1]));
      pk.y = __builtin_bit_cast(unsigned, __builtin_amdgcn_cvt_pkrtz(p[nt][2], p[nt][3]));
      *(uint2*)&Plds[w][lc][nt * 16 + 4 * lg] = pk;
    }
    f16x8 pa[2];
    pa[0] = *(const f16x8*)&Plds[w][lc][8 * lg];
    pa[1] = *(const f16x8*)&Plds[w][lc][32 + 8 * lg];

    // O += P V : A=P^T-row (M=q), B=V^T (N=d)
    #pragma unroll
    for (int nt = 0; nt < 4; ++nt)
      #pragma unroll
      for (int ks = 0; ks < 2; ++ks)
        o_acc[nt] = __builtin_amdgcn_mfma_f32_16x16x32_f16(pa[ks], vf[nt][ks], o_acc[nt], 0, 0, 0);
  }

  // epilogue: O /= l (broadcast l for rows 4*lg+r), coalesced dword stores
  float li[4];
  #pragma unroll
  for (int r = 0; r < 4; ++r) li[r] = 1.0f / __shfl(l_run, 4 * lg + r, 64);
  #pragma unroll
  for (int r = 0; r < 4; ++r) {
    float* orow = O + ((size_t)bh * Sc + q0 + w * 16 + 4 * lg + r) * Dc + lc;
    #pragma unroll
    for (int nt = 0; nt < 4; ++nt)
      orow[nt * 16] = o_acc[nt][r] * li[r];
  }
}

// ---------------- Fallback (round-1 kernel, used if ws too small) ----------------
constexpr int LDSW = KVBLK + 8;

__global__ __launch_bounds__(256)
void attn_fwd_v1(const float* __restrict__ Q, const float* __restrict__ K,
                 const float* __restrict__ V, const int* __restrict__ M,
                 float* __restrict__ O)
{
  const int bid   = blockIdx.x;
  const int qtile = bid & (NQ - 1);
  const int bh    = bid >> 5;
  const int b     = bh >> 4;

  const float* Qp = Q + ((size_t)bh * Sc + (size_t)qtile * QBLK) * Dc;
  const float* Kp = K + (size_t)bh * Sc * Dc;
  const float* Vp = V + (size_t)bh * Sc * Dc;
  const int*   Mp = M + (size_t)b * Sc * Sc + (size_t)qtile * QBLK * Sc;
  float*       Op = O + ((size_t)bh * Sc + (size_t)qtile * QBLK) * Dc;

  __shared__ _Float16 Klds [KVBLK][LDSW];
  __shared__ _Float16 Vtlds[Dc]   [LDSW];
  __shared__ _Float16 Plds [QBLK] [LDSW];

  const int tid = threadIdx.x;
  const int w   = tid >> 6;
  const int l   = tid & 63;
  const int lg  = l >> 4;
  const int lc  = l & 15;

  f16x8 qf[2];
  {
    const float qs = 0.125f * 1.4426950408889634f;
    const float* qrow = Qp + (size_t)(w * 16 + lc) * Dc + 8 * lg;
    #pragma unroll
    for (int ks = 0; ks < 2; ++ks) {
      f16x8 t;
      #pragma unroll
      for (int e = 0; e < 8; ++e) t[e] = (_Float16)(qrow[ks * 32 + e] * qs);
      qf[ks] = t;
    }
  }

  f32x4 o_acc[4];
  #pragma unroll
  for (int nt = 0; nt < 4; ++nt) o_acc[nt] = (f32x4){0.f, 0.f, 0.f, 0.f};
  float m_r[4], l_r[4];
  #pragma unroll
  for (int r = 0; r < 4; ++r) { m_r[r] = -3.0e38f; l_r[r] = 0.f; }

  const float NEGL = -1.4426950e9f;

  for (int kv = 0; kv < NKV; ++kv) {
    const float* Kt = Kp + (size_t)kv * KVBLK * Dc;
    const float* Vt = Vp + (size_t)kv * KVBLK * Dc;

    __syncthreads();
    {
      const int r = tid >> 2, c0 = (tid & 3) * 16;
      const float* src = Kt + (size_t)r * Dc + c0;
      f16x8 h0, h1;
      #pragma unroll
      for (int e = 0; e < 8; ++e) h0[e] = (_Float16)src[e];
      #pragma unroll
      for (int e = 0; e < 8; ++e) h1[e] = (_Float16)src[8 + e];
      *(f16x8*)&Klds[r][c0]     = h0;
      *(f16x8*)&Klds[r][c0 + 8] = h1;
    }
    {
      const int r0 = (tid >> 4) * 4, c0 = (tid & 15) * 4;
      float a_[4][4];
      #pragma unroll
      for (int i = 0; i < 4; ++i) {
        const float4 v4 = *(const float4*)(Vt + (size_t)(r0 + i) * Dc + c0);
        a_[i][0] = v4.x; a_[i][1] = v4.y; a_[i][2] = v4.z; a_[i][3] = v4.w;
      }
      #pragma unroll
      for (int j = 0; j < 4; ++j) {
        f16x4 t = {(_Float16)a_[0][j], (_Float16)a_[1][j],
                   (_Float16)a_[2][j], (_Float16)a_[3][j]};
        *(f16x4*)&Vtlds[c0 + j][r0] = t;
      }
    }
    __syncthreads();

    f32x4 s_acc[4];
    #pragma unroll
    for (int nt = 0; nt < 4; ++nt) {
      f32x4 acc = (f32x4){0.f, 0.f, 0.f, 0.f};
      #pragma unroll
      for (int ks = 0; ks < 2; ++ks) {
        f16x8 kf = *(const f16x8*)&Klds[nt * 16 + lc][ks * 32 + 8 * lg];
        acc = __builtin_amdgcn_mfma_f32_16x16x32_f16(qf[ks], kf, acc, 0, 0, 0);
      }
      s_acc[nt] = acc;
    }

    const int* mbase = Mp + (size_t)kv * KVBLK + lc;
    #pragma unroll
    for (int r = 0; r < 4; ++r) {
      const int qrow = w * 16 + 4 * lg + r;
      const int* mr = mbase + (size_t)qrow * Sc;
      float s0 = (mr[0]  != 0) ? s_acc[0][r] : NEGL;
      float s1 = (mr[16] != 0) ? s_acc[1][r] : NEGL;
      float s2 = (mr[32] != 0) ? s_acc[2][r] : NEGL;
      float s3 = (mr[48] != 0) ? s_acc[3][r] : NEGL;
      float mx = fmaxf(fmaxf(s0, s1), fmaxf(s2, s3));
      #pragma unroll
      for (int off = 1; off < 16; off <<= 1)
        mx = fmaxf(mx, __shfl_xor(mx, off, 64));
      const float mn   = fmaxf(m_r[r], mx);
      const float corr = fast_exp2(m_r[r] - mn);
      m_r[r] = mn;
      float p0 = fast_exp2(s0 - mn);
      float p1 = fast_exp2(s1 - mn);
      float p2 = fast_exp2(s2 - mn);
      float p3 = fast_exp2(s3 - mn);
      float rs = (p0 + p1) + (p2 + p3);
      #pragma unroll
      for (int off = 1; off < 16; off <<= 1)
        rs += __shfl_xor(rs, off, 64);
      l_r[r] = l_r[r] * corr + rs;
      #pragma unroll
      for (int nt = 0; nt < 4; ++nt) o_acc[nt][r] *= corr;
      Plds[qrow][lc]      = (_Float16)p0;
      Plds[qrow][16 + lc] = (_Float16)p1;
      Plds[qrow][32 + lc] = (_Float16)p2;
      Plds[qrow][48 + lc] = (_Float16)p3;
    }

    #pragma unroll
    for (int nt = 0; nt < 4; ++nt) {
      #pragma unroll
      for (int ks = 0; ks < 2; ++ks) {
        f16x8 pf = *(const f16x8*)&Plds [w * 16 + lc][ks * 32 + 8 * lg];
        f16x8 vf = *(const f16x8*)&Vtlds[nt * 16 + lc][ks * 32 + 8 * lg];
        o_acc[nt] = __builtin_amdgcn_mfma_f32_16x16x32_f16(pf, vf, o_acc[nt], 0, 0, 0);
      }
    }
  }

  #pragma unroll
  for (int r = 0; r < 4; ++r) {
    const float inv = 1.0f / l_r[r];
    float* orow = Op + (size_t)(w * 16 + 4 * lg + r) * Dc;
    #pragma unroll
    for (int nt = 0; nt < 4; ++nt)
      orow[nt * 16 + lc] = o_acc[nt][r] * inv;
  }
}

extern "C" void kernel_launch(void* const* d_in, const int* in_sizes, int n_in,
                              void* d_out, int out_size, void* d_ws, size_t ws_size,
                              hipStream_t stream) {
  (void)in_sizes; (void)n_in; (void)out_size;
  const float* Q = (const float*)d_in[0];
  const float* K = (const float*)d_in[1];
  const float* V = (const float*)d_in[2];
  const int*   M = (const int*)d_in[3];
  float*       O = (float*)d_out;

  const size_t nKV   = (size_t)Bc * Hc * Sc * Dc;          // 8,388,608 elements
  const size_t bytesK16 = nKV * 2;                          // 16 MiB
  const size_t bytesMB  = (size_t)Bc * NQ * NKV * 64 * 8;   // 2 MiB
  const size_t need     = 2 * bytesK16 + bytesMB;

  if (ws_size >= need) {
    _Float16* K16  = (_Float16*)d_ws;
    _Float16* Vt16 = (_Float16*)((char*)d_ws + bytesK16);
    u64*      MBp  = (u64*)((char*)d_ws + 2 * bytesK16);
    hipLaunchKernelGGL(cvt_k,       dim3(4096),  dim3(256), 0, stream, K, K16);
    hipLaunchKernelGGL(transpose_v, dim3(2048),  dim3(256), 0, stream, V, Vt16);
    hipLaunchKernelGGL(pack_mask,   dim3(65536), dim3(256), 0, stream, M, MBp);
    hipLaunchKernelGGL(attn_fwd2,   dim3(2048),  dim3(256), 0, stream, Q, K16, Vt16, MBp, O);
  } else {
    hipLaunchKernelGGL(attn_fwd_v1, dim3(2048),  dim3(256), 0, stream, Q, K, V, M, O);
  }
}

// Round 3
// 178.169 us; speedup vs baseline: 2.8583x; 2.8583x over previous
//
#include <hip/hip_runtime.h>

typedef _Float16 f16x8 __attribute__((ext_vector_type(8)));
typedef _Float16 f16x4 __attribute__((ext_vector_type(4)));
typedef float    f32x4 __attribute__((ext_vector_type(4)));
typedef unsigned long long u64;

constexpr int Bc = 4, Hc = 16, Sc = 2048, Dc = 64;
constexpr int KVBLK = 64;
constexpr int NKV = Sc / KVBLK;   // 32
constexpr int QB  = 128;          // q rows per block (8 waves x 16)
constexpr int NQT = Sc / QB;      // 16
constexpr int NQ  = 32;           // mask row-block granularity (64 rows)
constexpr int PW  = 80;           // Plds row stride in halves (160B: 16B-aligned, bank-uniform)

__device__ __forceinline__ float fast_exp2(float x) {
#if __has_builtin(__builtin_amdgcn_exp2f)
  return __builtin_amdgcn_exp2f(x);
#else
  return exp2f(x);
#endif
}

__device__ __forceinline__ void gload16(const void* g, void* l) {
  __builtin_amdgcn_global_load_lds(
      (const __attribute__((address_space(1))) void*)g,
      (__attribute__((address_space(3))) void*)l, 16, 0, 0);
}

// ---- Prepass A: K fp32 [bh][s][d] -> fp16 swizzled tiles [bh*32+kvt][512 chunks] ----
// chunk c (16B): row r=c>>3, slot s=c&7; holds source slot s^(r&7) (halves (s^(r&7))*8..+7 of row r)
__global__ __launch_bounds__(256)
void cvt_k_sw(const float* __restrict__ K, _Float16* __restrict__ Ko) {
  const int tile = blockIdx.x;              // bh*32 + kvt
  const int t = threadIdx.x;
  const float* src = K + (size_t)tile * 4096;
  _Float16* dst = Ko + (size_t)tile * 4096;
  #pragma unroll
  for (int cc = 0; cc < 2; ++cc) {
    const int c = t + cc * 256;
    const int r = c >> 3, s = c & 7;
    const int ss = s ^ (r & 7);
    const float* p = src + r * 64 + ss * 8;
    const float4 a = *(const float4*)p;
    const float4 b2 = *(const float4*)(p + 4);
    f16x8 h = {(_Float16)a.x, (_Float16)a.y, (_Float16)a.z, (_Float16)a.w,
               (_Float16)b2.x, (_Float16)b2.y, (_Float16)b2.z, (_Float16)b2.w};
    *(f16x8*)(dst + (size_t)c * 8) = h;
  }
}

// ---- Prepass B: V fp32 [bh][s][d] -> fp16 transposed+swizzled tiles [d-rows][key-cols] ----
__global__ __launch_bounds__(256)
void cvt_v_sw(const float* __restrict__ V, _Float16* __restrict__ Vo) {
  __shared__ float tile[64][65];
  const int tb = blockIdx.x;                // bh*32 + kvt
  const int t = threadIdx.x;
  const float* src = V + (size_t)tb * 4096;
  {
    const int r = t >> 2, c0 = (t & 3) * 16;
    #pragma unroll
    for (int j = 0; j < 16; j += 4)
      *(float4*)&tile[r][c0 + j] = *(const float4*)(src + r * 64 + c0 + j);
  }
  __syncthreads();
  _Float16* dst = Vo + (size_t)tb * 4096;
  #pragma unroll
  for (int cc = 0; cc < 2; ++cc) {
    const int c = t + cc * 256;
    const int d = c >> 3, s = c & 7;
    const int ss = s ^ (d & 7);
    f16x8 h;
    #pragma unroll
    for (int j = 0; j < 8; ++j) h[j] = (_Float16)tile[ss * 8 + j][d];
    *(f16x8*)(dst + (size_t)c * 8) = h;
  }
}

// ---- Prepass C: mask int32 -> bits[b][row>>6][kv][row&63] u64 ----
__global__ __launch_bounds__(256)
void pack_mask(const int* __restrict__ M, u64* __restrict__ MB) {
  const int gid  = blockIdx.x * 256 + threadIdx.x;
  const int wv   = gid >> 6, lane = gid & 63;
  const int kv   = wv & (NKV - 1);
  const int row  = (wv >> 5) & (Sc - 1);
  const int b    = wv >> 16;
  const int m    = M[((size_t)b * Sc + row) * Sc + (size_t)kv * 64 + lane];
  const u64 bits = __ballot(m != 0);
  if (lane == 0)
    MB[(((size_t)b * NQ + (row >> 6)) * NKV + kv) * 64 + (row & 63)] = bits;
}

// ---- Main: 2-phase pipelined flash attention, swapped QK^T, swizzled LDS ----
__global__ __launch_bounds__(512, 4)
void attn_fwd3(const float* __restrict__ Q, const _Float16* __restrict__ Ksw,
               const _Float16* __restrict__ Vsw, const u64* __restrict__ MB,
               float* __restrict__ O)
{
  // XCD-chunked swizzle: 1024 blocks = 8 XCDs x 128
  const int bid = (blockIdx.x & 7) * 128 + (blockIdx.x >> 3);
  const int qt  = bid & (NQT - 1);
  const int bh  = bid >> 4;
  const int b   = bh >> 4;
  const int q0  = qt * QB;

  const int tid = threadIdx.x;
  const int w   = tid >> 6;    // 0..7
  const int l   = tid & 63;
  const int lg  = l >> 4;      // 0..3
  const int lc  = l & 15;      // 0..15

  __shared__ _Float16 Kbuf0[4096], Kbuf1[4096];
  __shared__ _Float16 Vbuf0[4096], Vbuf1[4096];
  __shared__ _Float16 Plds[8][16][PW];

  // Q fragment (B operand): col=q=lc, k = ks*32+8*lg+e; scale*log2e folded
  f16x8 qf[2];
  {
    const float qs = 0.125f * 1.4426950408889634f;
    const float* qr = Q + ((size_t)bh * Sc + q0 + w * 16 + lc) * Dc + 8 * lg;
    #pragma unroll
    for (int ks = 0; ks < 2; ++ks) {
      f16x8 t;
      #pragma unroll
      for (int e = 0; e < 8; ++e) t[e] = (_Float16)(qr[ks * 32 + e] * qs);
      qf[ks] = t;
    }
  }

  f32x4 o_acc[4];
  #pragma unroll
  for (int nt = 0; nt < 4; ++nt) o_acc[nt] = (f32x4){0.f, 0.f, 0.f, 0.f};
  float m_run = -3.0e38f, l_run = 0.f;
  const float NEGL = -1.4426950e9f;

  const char* KswT = (const char*)(Ksw + (size_t)bh * Sc * Dc);
  const char* VswT = (const char*)(Vsw + (size_t)bh * Sc * Dc);
  const int row = q0 + w * 16 + lc;
  const u64* Mb = MB + ((size_t)(b * NQ + (row >> 6)) * NKV) * 64 + (row & 63);

  // swizzled slot offsets for ds_read (row&7 == lc&7 for all row = nt*16+lc)
  const int sw0 = (lg * 16) ^ ((lc & 7) << 4);
  const int sw1 = (64 + lg * 16) ^ ((lc & 7) << 4);

  auto stage = [&](int kvt, _Float16* kb, _Float16* vb) {
    const char* g = (w < 4) ? KswT + (size_t)kvt * 8192 + (w & 3) * 2048
                            : VswT + (size_t)kvt * 8192 + (w & 3) * 2048;
    char* lb = (w < 4) ? (char*)kb + (w & 3) * 2048
                       : (char*)vb + (w & 3) * 2048;
    gload16(g + l * 16, lb);
    gload16(g + 1024 + l * 16, lb + 1024);
  };

  auto body = [&](int kv, const _Float16* kb, const _Float16* vb) {
    const u64 mbits = Mb[(size_t)kv * 64];
    const char* Kb = (const char*)kb;
    // S^T = K Q^T : s_acc[nt][r] = S[key=nt*16+4*lg+r][q=lc]
    f32x4 s_acc[4];
    #pragma unroll
    for (int nt = 0; nt < 4; ++nt) {
      const f16x8 k0 = *(const f16x8*)(Kb + (nt * 16 + lc) * 128 + sw0);
      const f16x8 k1 = *(const f16x8*)(Kb + (nt * 16 + lc) * 128 + sw1);
      f32x4 acc = (f32x4){0.f, 0.f, 0.f, 0.f};
      acc = __builtin_amdgcn_mfma_f32_16x16x32_f16(k0, qf[0], acc, 0, 0, 0);
      acc = __builtin_amdgcn_mfma_f32_16x16x32_f16(k1, qf[1], acc, 0, 0, 0);
      s_acc[nt] = acc;
    }
    // mask select from packed bits
    float p[4][4];
    #pragma unroll
    for (int nt = 0; nt < 4; ++nt) {
      const unsigned b4 = ((unsigned)(mbits >> (nt * 16 + 4 * lg))) & 0xFu;
      #pragma unroll
      for (int r = 0; r < 4; ++r)
        p[nt][r] = ((b4 >> r) & 1u) ? s_acc[nt][r] : NEGL;
    }
    // online softmax for q=lc
    float mx = p[0][0];
    #pragma unroll
    for (int nt = 0; nt < 4; ++nt)
      #pragma unroll
      for (int r = 0; r < 4; ++r) mx = fmaxf(mx, p[nt][r]);
    mx = fmaxf(mx, __shfl_xor(mx, 16, 64));
    mx = fmaxf(mx, __shfl_xor(mx, 32, 64));
    const float mn   = fmaxf(m_run, mx);
    const float corr = fast_exp2(m_run - mn);
    m_run = mn;
    float rs = 0.f;
    #pragma unroll
    for (int nt = 0; nt < 4; ++nt)
      #pragma unroll
      for (int r = 0; r < 4; ++r) {
        const float pe = fast_exp2(p[nt][r] - mn);
        p[nt][r] = pe;
        rs += pe;
      }
    rs += __shfl_xor(rs, 16, 64);
    rs += __shfl_xor(rs, 32, 64);
    l_run = l_run * corr + rs;
    // rescale O rows (q = 4*lg+r): broadcast corr from lanes 0..15
    float cr[4];
    #pragma unroll
    for (int r = 0; r < 4; ++r) cr[r] = __shfl(corr, 4 * lg + r, 64);
    #pragma unroll
    for (int nt = 0; nt < 4; ++nt)
      #pragma unroll
      for (int r = 0; r < 4; ++r) o_acc[nt][r] *= cr[r];
    // P -> LDS (P^T[q][key]) as b64 writes; read back as A fragments
    #pragma unroll
    for (int nt = 0; nt < 4; ++nt) {
      uint2 pk;
      pk.x = __builtin_bit_cast(unsigned, __builtin_amdgcn_cvt_pkrtz(p[nt][0], p[nt][1]));
      pk.y = __builtin_bit_cast(unsigned, __builtin_amdgcn_cvt_pkrtz(p[nt][2], p[nt][3]));
      *(uint2*)&Plds[w][lc][nt * 16 + 4 * lg] = pk;
    }
    f16x8 pa0 = *(const f16x8*)&Plds[w][lc][8 * lg];
    f16x8 pa1 = *(const f16x8*)&Plds[w][lc][32 + 8 * lg];
    // O += P V : A = P^T row (M=q), B = V^T (N=d)
    const char* Vb = (const char*)vb;
    #pragma unroll
    for (int nt = 0; nt < 4; ++nt) {
      const f16x8 v0 = *(const f16x8*)(Vb + (nt * 16 + lc) * 128 + sw0);
      const f16x8 v1 = *(const f16x8*)(Vb + (nt * 16 + lc) * 128 + sw1);
      o_acc[nt] = __builtin_amdgcn_mfma_f32_16x16x32_f16(pa0, v0, o_acc[nt], 0, 0, 0);
      o_acc[nt] = __builtin_amdgcn_mfma_f32_16x16x32_f16(pa1, v1, o_acc[nt], 0, 0, 0);
    }
  };

  // ---- 2-phase pipeline, statically double-buffered ----
  stage(0, Kbuf0, Vbuf0);
  __syncthreads();
  for (int kv = 0; kv < NKV; kv += 2) {
    stage(kv + 1, Kbuf1, Vbuf1);      // prefetch next tile while computing current
    body(kv, Kbuf0, Vbuf0);
    __syncthreads();                  // drains this wave's loads + all waves done with buf0
    if (kv + 2 < NKV) stage(kv + 2, Kbuf0, Vbuf0);
    body(kv + 1, Kbuf1, Vbuf1);
    __syncthreads();
  }

  // ---- epilogue ----
  float li[4];
  #pragma unroll
  for (int r = 0; r < 4; ++r) li[r] = 1.0f / __shfl(l_run, 4 * lg + r, 64);
  #pragma unroll
  for (int r = 0; r < 4; ++r) {
    float* orow = O + ((size_t)bh * Sc + q0 + w * 16 + 4 * lg + r) * Dc + lc;
    #pragma unroll
    for (int nt = 0; nt < 4; ++nt)
      orow[nt * 16] = o_acc[nt][r] * li[r];
  }
}

// ---------------- Fallback (round-1 kernel, used if ws too small) ----------------
constexpr int LDSW = KVBLK + 8;

__global__ __launch_bounds__(256)
void attn_fwd_v1(const float* __restrict__ Q, const float* __restrict__ K,
                 const float* __restrict__ V, const int* __restrict__ M,
                 float* __restrict__ O)
{
  const int bid   = blockIdx.x;
  const int qtile = bid & 31;
  const int bh    = bid >> 5;
  const int b     = bh >> 4;

  const float* Qp = Q + ((size_t)bh * Sc + (size_t)qtile * 64) * Dc;
  const float* Kp = K + (size_t)bh * Sc * Dc;
  const float* Vp = V + (size_t)bh * Sc * Dc;
  const int*   Mp = M + (size_t)b * Sc * Sc + (size_t)qtile * 64 * Sc;
  float*       Op = O + ((size_t)bh * Sc + (size_t)qtile * 64) * Dc;

  __shared__ _Float16 Klds [KVBLK][LDSW];
  __shared__ _Float16 Vtlds[Dc]   [LDSW];
  __shared__ _Float16 Pl   [64]   [LDSW];

  const int tid = threadIdx.x;
  const int w   = tid >> 6;
  const int l   = tid & 63;
  const int lg  = l >> 4;
  const int lc  = l & 15;

  f16x8 qf[2];
  {
    const float qs = 0.125f * 1.4426950408889634f;
    const float* qrow = Qp + (size_t)(w * 16 + lc) * Dc + 8 * lg;
    #pragma unroll
    for (int ks = 0; ks < 2; ++ks) {
      f16x8 t;
      #pragma unroll
      for (int e = 0; e < 8; ++e) t[e] = (_Float16)(qrow[ks * 32 + e] * qs);
      qf[ks] = t;
    }
  }

  f32x4 o_acc[4];
  #pragma unroll
  for (int nt = 0; nt < 4; ++nt) o_acc[nt] = (f32x4){0.f, 0.f, 0.f, 0.f};
  float m_r[4], l_r[4];
  #pragma unroll
  for (int r = 0; r < 4; ++r) { m_r[r] = -3.0e38f; l_r[r] = 0.f; }
  const float NEGL = -1.4426950e9f;

  for (int kv = 0; kv < NKV; ++kv) {
    const float* Kt = Kp + (size_t)kv * KVBLK * Dc;
    const float* Vt = Vp + (size_t)kv * KVBLK * Dc;
    __syncthreads();
    {
      const int r = tid >> 2, c0 = (tid & 3) * 16;
      const float* src = Kt + (size_t)r * Dc + c0;
      f16x8 h0, h1;
      #pragma unroll
      for (int e = 0; e < 8; ++e) h0[e] = (_Float16)src[e];
      #pragma unroll
      for (int e = 0; e < 8; ++e) h1[e] = (_Float16)src[8 + e];
      *(f16x8*)&Klds[r][c0]     = h0;
      *(f16x8*)&Klds[r][c0 + 8] = h1;
    }
    {
      const int r0 = (tid >> 4) * 4, c0 = (tid & 15) * 4;
      float a_[4][4];
      #pragma unroll
      for (int i = 0; i < 4; ++i) {
        const float4 v4 = *(const float4*)(Vt + (size_t)(r0 + i) * Dc + c0);
        a_[i][0] = v4.x; a_[i][1] = v4.y; a_[i][2] = v4.z; a_[i][3] = v4.w;
      }
      #pragma unroll
      for (int j = 0; j < 4; ++j) {
        f16x4 t = {(_Float16)a_[0][j], (_Float16)a_[1][j],
                   (_Float16)a_[2][j], (_Float16)a_[3][j]};
        *(f16x4*)&Vtlds[c0 + j][r0] = t;
      }
    }
    __syncthreads();

    f32x4 s_acc[4];
    #pragma unroll
    for (int nt = 0; nt < 4; ++nt) {
      f32x4 acc = (f32x4){0.f, 0.f, 0.f, 0.f};
      #pragma unroll
      for (int ks = 0; ks < 2; ++ks) {
        f16x8 kf = *(const f16x8*)&Klds[nt * 16 + lc][ks * 32 + 8 * lg];
        acc = __builtin_amdgcn_mfma_f32_16x16x32_f16(qf[ks], kf, acc, 0, 0, 0);
      }
      s_acc[nt] = acc;
    }

    const int* mbase = Mp + (size_t)kv * KVBLK + lc;
    #pragma unroll
    for (int r = 0; r < 4; ++r) {
      const int qrow = w * 16 + 4 * lg + r;
      const int* mr = mbase + (size_t)qrow * Sc;
      float s0 = (mr[0]  != 0) ? s_acc[0][r] : NEGL;
      float s1 = (mr[16] != 0) ? s_acc[1][r] : NEGL;
      float s2 = (mr[32] != 0) ? s_acc[2][r] : NEGL;
      float s3 = (mr[48] != 0) ? s_acc[3][r] : NEGL;
      float mx = fmaxf(fmaxf(s0, s1), fmaxf(s2, s3));
      #pragma unroll
      for (int off = 1; off < 16; off <<= 1)
        mx = fmaxf(mx, __shfl_xor(mx, off, 64));
      const float mn   = fmaxf(m_r[r], mx);
      const float corr = fast_exp2(m_r[r] - mn);
      m_r[r] = mn;
      float p0 = fast_exp2(s0 - mn);
      float p1 = fast_exp2(s1 - mn);
      float p2 = fast_exp2(s2 - mn);
      float p3 = fast_exp2(s3 - mn);
      float rs = (p0 + p1) + (p2 + p3);
      #pragma unroll
      for (int off = 1; off < 16; off <<= 1)
        rs += __shfl_xor(rs, off, 64);
      l_r[r] = l_r[r] * corr + rs;
      #pragma unroll
      for (int nt = 0; nt < 4; ++nt) o_acc[nt][r] *= corr;
      Pl[qrow][lc]      = (_Float16)p0;
      Pl[qrow][16 + lc] = (_Float16)p1;
      Pl[qrow][32 + lc] = (_Float16)p2;
      Pl[qrow][48 + lc] = (_Float16)p3;
    }

    #pragma unroll
    for (int nt = 0; nt < 4; ++nt) {
      #pragma unroll
      for (int ks = 0; ks < 2; ++ks) {
        f16x8 pf = *(const f16x8*)&Pl[w * 16 + lc][ks * 32 + 8 * lg];
        f16x8 vf = *(const f16x8*)&Vtlds[nt * 16 + lc][ks * 32 + 8 * lg];
        o_acc[nt] = __builtin_amdgcn_mfma_f32_16x16x32_f16(pf, vf, o_acc[nt], 0, 0, 0);
      }
    }
  }

  #pragma unroll
  for (int r = 0; r < 4; ++r) {
    const float inv = 1.0f / l_r[r];
    float* orow = Op + (size_t)(w * 16 + 4 * lg + r) * Dc;
    #pragma unroll
    for (int nt = 0; nt < 4; ++nt)
      orow[nt * 16 + lc] = o_acc[nt][r] * inv;
  }
}

extern "C" void kernel_launch(void* const* d_in, const int* in_sizes, int n_in,
                              void* d_out, int out_size, void* d_ws, size_t ws_size,
                              hipStream_t stream) {
  (void)in_sizes; (void)n_in; (void)out_size;
  const float* Q = (const float*)d_in[0];
  const float* K = (const float*)d_in[1];
  const float* V = (const float*)d_in[2];
  const int*   M = (const int*)d_in[3];
  float*       O = (float*)d_out;

  const size_t nKV      = (size_t)Bc * Hc * Sc * Dc;        // 8,388,608
  const size_t bytesK16 = nKV * 2;                           // 16 MiB
  const size_t bytesMB  = (size_t)Bc * NQ * NKV * 64 * 8;    // 2 MiB
  const size_t need     = 2 * bytesK16 + bytesMB;

  if (ws_size >= need) {
    _Float16* K16  = (_Float16*)d_ws;
    _Float16* Vt16 = (_Float16*)((char*)d_ws + bytesK16);
    u64*      MBp  = (u64*)((char*)d_ws + 2 * bytesK16);
    hipLaunchKernelGGL(cvt_k_sw,  dim3(2048),  dim3(256), 0, stream, K, K16);
    hipLaunchKernelGGL(cvt_v_sw,  dim3(2048),  dim3(256), 0, stream, V, Vt16);
    hipLaunchKernelGGL(pack_mask, dim3(65536), dim3(256), 0, stream, M, MBp);
    hipLaunchKernelGGL(attn_fwd3, dim3(1024),  dim3(512), 0, stream, Q, K16, Vt16, MBp, O);
  } else {
    hipLaunchKernelGGL(attn_fwd_v1, dim3(2048), dim3(256), 0, stream, Q, K, V, M, O);
  }
}